// Round 1
// baseline (491.933 us; speedup 1.0000x reference)
//
#include <hip/hip_runtime.h>
#include <hip/hip_bf16.h>
#include <stdint.h>

// Problem: B=2, S=2048, D=1024, H=16, HD=64.
// KL bias term is a per-row constant added to scores -> softmax-invariant -> dropped.
// out = softmax(QK^T/8) V with 4 dense projections. bf16 MFMA, fp32 accum.

#define NB 2
#define NS 2048
#define ND 1024
#define NH 16
#define HD 64
#define MROWS (NB * NS)   // 4096

typedef short bf16x8 __attribute__((ext_vector_type(8)));
typedef short bf16x4 __attribute__((ext_vector_type(4)));
typedef float f32x4 __attribute__((ext_vector_type(4)));

static __device__ __forceinline__ short f2bf(float f) {
    uint32_t u = __builtin_bit_cast(uint32_t, f);
    uint32_t r = (u + 0x7fffu + ((u >> 16) & 1u)) >> 16;
    return (short)(uint16_t)r;
}

// ---------------------------------------------------------------------------
// Prep: Wt[n][k] = bf16(W[k][n]) for the 4 weight matrices (z = which).
// ---------------------------------------------------------------------------
__global__ __launch_bounds__(256) void prep_wt(const float* __restrict__ W0,
                                               const float* __restrict__ W1,
                                               const float* __restrict__ W2,
                                               const float* __restrict__ W3,
                                               short* __restrict__ WtAll) {
    __shared__ short tile[32][33];
    const float* W = (blockIdx.z == 0) ? W0 : (blockIdx.z == 1) ? W1
                   : (blockIdx.z == 2) ? W2 : W3;
    short* Wt = WtAll + (size_t)blockIdx.z * (ND * ND);
    const int tx = threadIdx.x & 31;
    const int ty = threadIdx.x >> 5;  // 0..7
    const int k0 = blockIdx.x * 32, n0 = blockIdx.y * 32;
#pragma unroll
    for (int i = 0; i < 4; i++)
        tile[ty + i * 8][tx] = f2bf(W[(size_t)(k0 + ty + i * 8) * ND + n0 + tx]);
    __syncthreads();
#pragma unroll
    for (int i = 0; i < 4; i++)
        Wt[(size_t)(n0 + ty + i * 8) * ND + k0 + tx] = tile[tx][ty + i * 8];
}

// ---------------------------------------------------------------------------
// GEMM: C[M=4096, N=1024] = A[4096,1024] @ W[1024,1024] + bias
//   A is fp32 (modes 0/1) or bf16 (mode 3). Wt is bf16 pre-transposed [n][k].
//   MODE 0: out bf16 [b][h][s][hd]    (Q, K)
//   MODE 1: out bf16 [b][h][hd][s]    (V transposed for PV fragments)
//   MODE 3: out fp32 row-major (final output), A bf16
// 128x128 tile, BK=32, 256 threads (4 waves, each 64x64 via 4x4 MFMA frags).
// ---------------------------------------------------------------------------
#define LDA 40  // LDS row stride (bf16 elems): 80B, 16B-aligned, conflict-light

template <int MODE>
__global__ __launch_bounds__(256) void gemm_kern(const void* __restrict__ Aptr,
                                                 const short* __restrict__ Wt,
                                                 const float* __restrict__ bias,
                                                 void* __restrict__ Out) {
    constexpr bool A_F32 = (MODE != 3);
    __shared__ short As[128 * LDA];
    __shared__ short Bs[128 * LDA];

    const int tid = threadIdx.x;
    const int gm = blockIdx.x * 128;
    const int gn = blockIdx.y * 128;
    const int w = tid >> 6;
    const int l = tid & 63;
    const int r = l & 15;
    const int g = l >> 4;
    const int wr = w >> 1, wc = w & 1;

    f32x4 acc[4][4];
#pragma unroll
    for (int m = 0; m < 4; m++)
#pragma unroll
        for (int n = 0; n < 4; n++) acc[m][n] = (f32x4){0.f, 0.f, 0.f, 0.f};

    const int srow = tid >> 1;   // 0..127
    const int shalf = tid & 1;   // k sub-offset 0 / 16

    for (int k0 = 0; k0 < ND; k0 += 32) {
        // ---- stage A tile: As[row][k] (bf16)
        if constexpr (A_F32) {
            const float* A = (const float*)Aptr;
            const f32x4* src =
                (const f32x4*)(A + (size_t)(gm + srow) * ND + k0 + shalf * 16);
            f32x4 v0 = src[0], v1 = src[1], v2 = src[2], v3 = src[3];
            bf16x8 o0, o1;
            o0[0] = f2bf(v0[0]); o0[1] = f2bf(v0[1]); o0[2] = f2bf(v0[2]); o0[3] = f2bf(v0[3]);
            o0[4] = f2bf(v1[0]); o0[5] = f2bf(v1[1]); o0[6] = f2bf(v1[2]); o0[7] = f2bf(v1[3]);
            o1[0] = f2bf(v2[0]); o1[1] = f2bf(v2[1]); o1[2] = f2bf(v2[2]); o1[3] = f2bf(v2[3]);
            o1[4] = f2bf(v3[0]); o1[5] = f2bf(v3[1]); o1[6] = f2bf(v3[2]); o1[7] = f2bf(v3[3]);
            *(bf16x8*)&As[srow * LDA + shalf * 16] = o0;
            *(bf16x8*)&As[srow * LDA + shalf * 16 + 8] = o1;
        } else {
            const short* A = (const short*)Aptr;
            const bf16x8* src =
                (const bf16x8*)(A + (size_t)(gm + srow) * ND + k0 + shalf * 16);
            *(bf16x8*)&As[srow * LDA + shalf * 16] = src[0];
            *(bf16x8*)&As[srow * LDA + shalf * 16 + 8] = src[1];
        }
        // ---- stage B tile: Bs[n][k] = Wt[gn+n][k0+k] (already bf16, contiguous k)
        {
            const bf16x8* src =
                (const bf16x8*)(Wt + (size_t)(gn + srow) * ND + k0 + shalf * 16);
            *(bf16x8*)&Bs[srow * LDA + shalf * 16] = src[0];
            *(bf16x8*)&Bs[srow * LDA + shalf * 16 + 8] = src[1];
        }
        __syncthreads();

        bf16x8 af[4], bfv[4];
#pragma unroll
        for (int m = 0; m < 4; m++)
            af[m] = *(const bf16x8*)&As[(wr * 64 + m * 16 + r) * LDA + g * 8];
#pragma unroll
        for (int n = 0; n < 4; n++)
            bfv[n] = *(const bf16x8*)&Bs[(wc * 64 + n * 16 + r) * LDA + g * 8];
#pragma unroll
        for (int m = 0; m < 4; m++)
#pragma unroll
            for (int n = 0; n < 4; n++)
                acc[m][n] = __builtin_amdgcn_mfma_f32_16x16x32_bf16(
                    af[m], bfv[n], acc[m][n], 0, 0, 0);
        __syncthreads();
    }

    // ---- epilogue. C/D layout (verified): reg i of lane l -> row 4*(l>>4)+i, col l&15
#pragma unroll
    for (int m = 0; m < 4; m++) {
        const int orow = gm + wr * 64 + m * 16 + g * 4;
#pragma unroll
        for (int n = 0; n < 4; n++) {
            const int ocol = gn + wc * 64 + n * 16 + r;
            const float bv = bias[ocol];
#pragma unroll
            for (int i = 0; i < 4; i++) {
                const float vout = acc[m][n][i] + bv;
                const int row = orow + i;
                if constexpr (MODE == 0) {
                    const int b = row >> 11, s = row & 2047;
                    const int h = ocol >> 6, hd = ocol & 63;
                    ((short*)Out)[(((size_t)(b * NH + h) * NS + s) << 6) + hd] = f2bf(vout);
                } else if constexpr (MODE == 1) {
                    const int b = row >> 11, s = row & 2047;
                    const int h = ocol >> 6, hd = ocol & 63;
                    ((short*)Out)[((size_t)(b * NH + h) * HD + hd) * NS + s] = f2bf(vout);
                } else {
                    ((float*)Out)[(size_t)row * ND + ocol] = vout;
                }
            }
        }
    }
}

// ---------------------------------------------------------------------------
// Attention: per wave = 16 q rows; per (b,h) iterate all 2048 keys in 32-chunks.
// S^T = K @ Q^T so P lives in C/D layout with q = lane&15 -> row-sum is a
// 4-group cross-lane reduce, and exp(P) feeds the PV MFMA directly as the
// B operand under a consistent k-permutation (no LDS transpose).
// Un-normalized single-pass softmax (scores ~2, no overflow possible).
// ---------------------------------------------------------------------------
__global__ __launch_bounds__(256) void attn_kern(const short* __restrict__ Q,
                                                 const short* __restrict__ K,
                                                 const short* __restrict__ Vt,
                                                 short* __restrict__ Ctx) {
    const int tid = threadIdx.x;
    const int w = tid >> 6;
    const int l = tid & 63;
    const int r = l & 15;
    const int g = l >> 4;
    const int bh = blockIdx.y;                 // b*16 + h
    const int qb = blockIdx.x * 64 + w * 16;   // this wave's q base

    const short* Qp = Q + (size_t)bh * NS * HD;
    const short* Kp = K + (size_t)bh * NS * HD;
    const short* Vp = Vt + (size_t)bh * HD * NS;

    // Q fragments (B operand of S^T mfma): lane holds Q[qb+r][c2*32 + 8g .. +7]
    bf16x8 qf0 = *(const bf16x8*)(Qp + (size_t)(qb + r) * HD + g * 8);
    bf16x8 qf1 = *(const bf16x8*)(Qp + (size_t)(qb + r) * HD + 32 + g * 8);

    f32x4 acc[4];
#pragma unroll
    for (int dt = 0; dt < 4; dt++) acc[dt] = (f32x4){0.f, 0.f, 0.f, 0.f};
    float rsum = 0.f;

    for (int kt = 0; kt < NS; kt += 32) {
        f32x4 T0 = (f32x4){0.f, 0.f, 0.f, 0.f};
        f32x4 T1 = (f32x4){0.f, 0.f, 0.f, 0.f};
        {
            bf16x8 k00 = *(const bf16x8*)(Kp + (size_t)(kt + r) * HD + g * 8);
            bf16x8 k01 = *(const bf16x8*)(Kp + (size_t)(kt + r) * HD + 32 + g * 8);
            T0 = __builtin_amdgcn_mfma_f32_16x16x32_bf16(k00, qf0, T0, 0, 0, 0);
            T0 = __builtin_amdgcn_mfma_f32_16x16x32_bf16(k01, qf1, T0, 0, 0, 0);
            bf16x8 k10 = *(const bf16x8*)(Kp + (size_t)(kt + 16 + r) * HD + g * 8);
            bf16x8 k11 = *(const bf16x8*)(Kp + (size_t)(kt + 16 + r) * HD + 32 + g * 8);
            T1 = __builtin_amdgcn_mfma_f32_16x16x32_bf16(k10, qf0, T1, 0, 0, 0);
            T1 = __builtin_amdgcn_mfma_f32_16x16x32_bf16(k11, qf1, T1, 0, 0, 0);
        }
        // P = exp(score); lane reg i of T0 holds S^T[k=kt+4g+i][q=qb+r], T1: k+16
        float p0[4], p1[4];
#pragma unroll
        for (int i = 0; i < 4; i++) {
            p0[i] = __expf(T0[i] * 0.125f);
            p1[i] = __expf(T1[i] * 0.125f);
            rsum += p0[i] + p1[i];
        }
        bf16x8 pf;
        pf[0] = f2bf(p0[0]); pf[1] = f2bf(p0[1]); pf[2] = f2bf(p0[2]); pf[3] = f2bf(p0[3]);
        pf[4] = f2bf(p1[0]); pf[5] = f2bf(p1[1]); pf[6] = f2bf(p1[2]); pf[7] = f2bf(p1[3]);
        // PV: A = Vt rows (d), k-map j=0..3 -> kt+4g+j ; j=4..7 -> kt+16+4g+(j-4)
#pragma unroll
        for (int dt = 0; dt < 4; dt++) {
            bf16x4 v0 = *(const bf16x4*)(Vp + (size_t)(dt * 16 + r) * NS + kt + g * 4);
            bf16x4 v1 = *(const bf16x4*)(Vp + (size_t)(dt * 16 + r) * NS + kt + 16 + g * 4);
            bf16x8 vf;
            vf[0] = v0[0]; vf[1] = v0[1]; vf[2] = v0[2]; vf[3] = v0[3];
            vf[4] = v1[0]; vf[5] = v1[1]; vf[6] = v1[2]; vf[7] = v1[3];
            acc[dt] = __builtin_amdgcn_mfma_f32_16x16x32_bf16(vf, pf, acc[dt], 0, 0, 0);
        }
    }

    rsum += __shfl_xor(rsum, 16);
    rsum += __shfl_xor(rsum, 32);
    const float inv = 1.0f / rsum;

    const int b = bh >> 4, h = bh & 15;
    short* ctxp = Ctx + ((size_t)b * NS + qb + r) * ND + h * HD;
#pragma unroll
    for (int dt = 0; dt < 4; dt++)
#pragma unroll
        for (int i = 0; i < 4; i++)
            ctxp[dt * 16 + g * 4 + i] = f2bf(acc[dt][i] * inv);
}

// ---------------------------------------------------------------------------
extern "C" void kernel_launch(void* const* d_in, const int* in_sizes, int n_in,
                              void* d_out, int out_size, void* d_ws, size_t ws_size,
                              hipStream_t stream) {
    (void)in_sizes; (void)n_in; (void)out_size; (void)ws_size;
    const float* query = (const float*)d_in[0];
    const float* key_  = (const float*)d_in[1];
    const float* value = (const float*)d_in[2];
    const float* Wq = (const float*)d_in[3];
    const float* bq = (const float*)d_in[4];
    const float* Wk = (const float*)d_in[5];
    const float* bk = (const float*)d_in[6];
    const float* Wv = (const float*)d_in[7];
    const float* bv = (const float*)d_in[8];
    const float* Wo = (const float*)d_in[9];
    const float* bo = (const float*)d_in[10];

    // ws layout (bytes): Wt x4 @0 (8 MiB), Q @8M, K @16M, Vt @24M, Ctx @32M  (40 MiB)
    char* ws = (char*)d_ws;
    short* WtAll = (short*)ws;
    short* Qb  = (short*)(ws + (size_t)8 * 1024 * 1024);
    short* Kb  = (short*)(ws + (size_t)16 * 1024 * 1024);
    short* Vtb = (short*)(ws + (size_t)24 * 1024 * 1024);
    short* Ctx = (short*)(ws + (size_t)32 * 1024 * 1024);

    prep_wt<<<dim3(32, 32, 4), 256, 0, stream>>>(Wq, Wk, Wv, Wo, WtAll);
    gemm_kern<0><<<dim3(32, 8), 256, 0, stream>>>(query, WtAll,                bq, Qb);
    gemm_kern<0><<<dim3(32, 8), 256, 0, stream>>>(key_,  WtAll + 1 * ND * ND,  bk, Kb);
    gemm_kern<1><<<dim3(32, 8), 256, 0, stream>>>(value, WtAll + 2 * ND * ND,  bv, Vtb);
    attn_kern<<<dim3(32, 32), 256, 0, stream>>>(Qb, Kb, Vtb, Ctx);
    gemm_kern<3><<<dim3(32, 8), 256, 0, stream>>>(Ctx, WtAll + 3 * ND * ND, bo, d_out);
}

// Round 2
// 329.480 us; speedup vs baseline: 1.4931x; 1.4931x over previous
//
#include <hip/hip_runtime.h>
#include <hip/hip_bf16.h>
#include <stdint.h>

// Problem: B=2, S=2048, D=1024, H=16, HD=64.
// KL bias term is a per-row constant added to scores -> softmax-invariant -> dropped.
// out = softmax(QK^T/8) V with 4 dense projections. bf16 MFMA, fp32 accum.

#define NB 2
#define NS 2048
#define ND 1024
#define NH 16
#define HD 64
#define MROWS (NB * NS)   // 4096

typedef short bf16x8 __attribute__((ext_vector_type(8)));
typedef short bf16x4 __attribute__((ext_vector_type(4)));
typedef float f32x4 __attribute__((ext_vector_type(4)));

static __device__ __forceinline__ short f2bf(float f) {
    uint32_t u = __builtin_bit_cast(uint32_t, f);
    uint32_t r = (u + 0x7fffu + ((u >> 16) & 1u)) >> 16;
    return (short)(uint16_t)r;
}

// ---------------------------------------------------------------------------
// Prep: Wt[n][k] = bf16(W[k][n]) for the 4 weight matrices (z = which).
// ---------------------------------------------------------------------------
__global__ __launch_bounds__(256) void prep_wt(const float* __restrict__ W0,
                                               const float* __restrict__ W1,
                                               const float* __restrict__ W2,
                                               const float* __restrict__ W3,
                                               short* __restrict__ WtAll) {
    __shared__ short tile[32][33];
    const float* W = (blockIdx.z == 0) ? W0 : (blockIdx.z == 1) ? W1
                   : (blockIdx.z == 2) ? W2 : W3;
    short* Wt = WtAll + (size_t)blockIdx.z * (ND * ND);
    const int tx = threadIdx.x & 31;
    const int ty = threadIdx.x >> 5;  // 0..7
    const int k0 = blockIdx.x * 32, n0 = blockIdx.y * 32;
#pragma unroll
    for (int i = 0; i < 4; i++)
        tile[ty + i * 8][tx] = f2bf(W[(size_t)(k0 + ty + i * 8) * ND + n0 + tx]);
    __syncthreads();
#pragma unroll
    for (int i = 0; i < 4; i++)
        Wt[(size_t)(n0 + ty + i * 8) * ND + k0 + tx] = tile[tx][ty + i * 8];
}

// ---------------------------------------------------------------------------
// GEMM: C[M=4096, N=1024] = A[4096,1024] @ W[1024,1024] + bias
//   A is fp32 (modes 0/1) or bf16 (mode 3). Wt is bf16 pre-transposed [n][k].
//   MODE 0: out bf16 [b][h][s][hd]    (Q, K)
//   MODE 1: out bf16 [b][h][hd][s]    (V transposed for PV fragments)
//   MODE 3: out fp32 row-major (final output), A bf16
// 128x128 tile, BK=32, 256 threads (4 waves, each 64x64 via 4x4 MFMA frags).
// ---------------------------------------------------------------------------
#define LDA 40  // LDS row stride (bf16 elems): 80B, 16B-aligned, conflict-light

template <int MODE>
__global__ __launch_bounds__(256) void gemm_kern(const void* __restrict__ Aptr,
                                                 const short* __restrict__ Wt,
                                                 const float* __restrict__ bias,
                                                 void* __restrict__ Out) {
    constexpr bool A_F32 = (MODE != 3);
    __shared__ short As[128 * LDA];
    __shared__ short Bs[128 * LDA];

    const int tid = threadIdx.x;
    const int gm = blockIdx.x * 128;
    const int gn = blockIdx.y * 128;
    const int w = tid >> 6;
    const int l = tid & 63;
    const int r = l & 15;
    const int g = l >> 4;
    const int wr = w >> 1, wc = w & 1;

    f32x4 acc[4][4];
#pragma unroll
    for (int m = 0; m < 4; m++)
#pragma unroll
        for (int n = 0; n < 4; n++) acc[m][n] = (f32x4){0.f, 0.f, 0.f, 0.f};

    const int srow = tid >> 1;   // 0..127
    const int shalf = tid & 1;   // k sub-offset 0 / 16

    for (int k0 = 0; k0 < ND; k0 += 32) {
        // ---- stage A tile: As[row][k] (bf16)
        if constexpr (A_F32) {
            const float* A = (const float*)Aptr;
            const f32x4* src =
                (const f32x4*)(A + (size_t)(gm + srow) * ND + k0 + shalf * 16);
            f32x4 v0 = src[0], v1 = src[1], v2 = src[2], v3 = src[3];
            bf16x8 o0, o1;
            o0[0] = f2bf(v0[0]); o0[1] = f2bf(v0[1]); o0[2] = f2bf(v0[2]); o0[3] = f2bf(v0[3]);
            o0[4] = f2bf(v1[0]); o0[5] = f2bf(v1[1]); o0[6] = f2bf(v1[2]); o0[7] = f2bf(v1[3]);
            o1[0] = f2bf(v2[0]); o1[1] = f2bf(v2[1]); o1[2] = f2bf(v2[2]); o1[3] = f2bf(v2[3]);
            o1[4] = f2bf(v3[0]); o1[5] = f2bf(v3[1]); o1[6] = f2bf(v3[2]); o1[7] = f2bf(v3[3]);
            *(bf16x8*)&As[srow * LDA + shalf * 16] = o0;
            *(bf16x8*)&As[srow * LDA + shalf * 16 + 8] = o1;
        } else {
            const short* A = (const short*)Aptr;
            const bf16x8* src =
                (const bf16x8*)(A + (size_t)(gm + srow) * ND + k0 + shalf * 16);
            *(bf16x8*)&As[srow * LDA + shalf * 16] = src[0];
            *(bf16x8*)&As[srow * LDA + shalf * 16 + 8] = src[1];
        }
        // ---- stage B tile: Bs[n][k] = Wt[gn+n][k0+k] (already bf16, contiguous k)
        {
            const bf16x8* src =
                (const bf16x8*)(Wt + (size_t)(gn + srow) * ND + k0 + shalf * 16);
            *(bf16x8*)&Bs[srow * LDA + shalf * 16] = src[0];
            *(bf16x8*)&Bs[srow * LDA + shalf * 16 + 8] = src[1];
        }
        __syncthreads();

        bf16x8 af[4], bfv[4];
#pragma unroll
        for (int m = 0; m < 4; m++)
            af[m] = *(const bf16x8*)&As[(wr * 64 + m * 16 + r) * LDA + g * 8];
#pragma unroll
        for (int n = 0; n < 4; n++)
            bfv[n] = *(const bf16x8*)&Bs[(wc * 64 + n * 16 + r) * LDA + g * 8];
#pragma unroll
        for (int m = 0; m < 4; m++)
#pragma unroll
            for (int n = 0; n < 4; n++)
                acc[m][n] = __builtin_amdgcn_mfma_f32_16x16x32_bf16(
                    af[m], bfv[n], acc[m][n], 0, 0, 0);
        __syncthreads();
    }

    // ---- epilogue. C/D layout (verified): reg i of lane l -> row 4*(l>>4)+i, col l&15
#pragma unroll
    for (int m = 0; m < 4; m++) {
        const int orow = gm + wr * 64 + m * 16 + g * 4;
#pragma unroll
        for (int n = 0; n < 4; n++) {
            const int ocol = gn + wc * 64 + n * 16 + r;
            const float bv = bias[ocol];
#pragma unroll
            for (int i = 0; i < 4; i++) {
                const float vout = acc[m][n][i] + bv;
                const int row = orow + i;
                if constexpr (MODE == 0) {
                    const int b = row >> 11, s = row & 2047;
                    const int h = ocol >> 6, hd = ocol & 63;
                    ((short*)Out)[(((size_t)(b * NH + h) * NS + s) << 6) + hd] = f2bf(vout);
                } else if constexpr (MODE == 1) {
                    const int b = row >> 11, s = row & 2047;
                    const int h = ocol >> 6, hd = ocol & 63;
                    ((short*)Out)[((size_t)(b * NH + h) * HD + hd) * NS + s] = f2bf(vout);
                } else {
                    ((float*)Out)[(size_t)row * ND + ocol] = vout;
                }
            }
        }
    }
}

// ---------------------------------------------------------------------------
// Attention v2: block = 4 waves, ONE 32-q tile, key-split: wave w handles keys
// [w*512, w*512+512). Each wave: 32 q rows (two 16-row halves sharing K/V
// fragments). Un-normalized single-pass softmax (scores ~2, no overflow), so
// disjoint-key partials combine linearly in the LDS epilogue.
// S^T = K @ Q^T (16x16x32, round-1-verified lane maps); exp(P) feeds PV MFMA
// directly as B operand under a consistent k-permutation.
// ---------------------------------------------------------------------------
__global__ __launch_bounds__(256, 4) void attn_kern(const short* __restrict__ Q,
                                                    const short* __restrict__ K,
                                                    const short* __restrict__ Vt,
                                                    short* __restrict__ Ctx) {
    __shared__ float red[4][32][65];
    __shared__ float redsum[4][32];

    const int tid = threadIdx.x;
    const int w = tid >> 6;    // key-split slot
    const int l = tid & 63;
    const int r = l & 15;
    const int g = l >> 4;
    const int bh = blockIdx.y;              // b*16 + h
    const int qb = blockIdx.x * 32;         // block's q base

    const short* Qp = Q + (size_t)bh * NS * HD;
    const short* Kp = K + (size_t)bh * NS * HD;
    const short* Vp = Vt + (size_t)bh * HD * NS;

    // Q fragments (B operand): qf[qh][c] -> Q[qb+16qh+r][c*32 + 8g .. +7]
    bf16x8 qf[2][2];
#pragma unroll
    for (int qh = 0; qh < 2; qh++) {
#pragma unroll
        for (int c = 0; c < 2; c++)
            qf[qh][c] = *(const bf16x8*)(Qp + (size_t)(qb + 16 * qh + r) * HD + c * 32 + g * 8);
    }

    f32x4 acc[2][4];
#pragma unroll
    for (int qh = 0; qh < 2; qh++)
#pragma unroll
        for (int dt = 0; dt < 4; dt++) acc[qh][dt] = (f32x4){0.f, 0.f, 0.f, 0.f};
    float rsum[2] = {0.f, 0.f};

    const int kbeg = w * (NS / 4);
    const int kend = kbeg + (NS / 4);
    for (int kt = kbeg; kt < kend; kt += 32) {
        // K fragments (A operand), shared by both q-halves
        bf16x8 k00 = *(const bf16x8*)(Kp + (size_t)(kt + r) * HD + g * 8);
        bf16x8 k01 = *(const bf16x8*)(Kp + (size_t)(kt + r) * HD + 32 + g * 8);
        bf16x8 k10 = *(const bf16x8*)(Kp + (size_t)(kt + 16 + r) * HD + g * 8);
        bf16x8 k11 = *(const bf16x8*)(Kp + (size_t)(kt + 16 + r) * HD + 32 + g * 8);

        // V fragments (A operand of PV), shared by both q-halves
        bf16x8 vf[4];
#pragma unroll
        for (int dt = 0; dt < 4; dt++) {
            bf16x4 v0 = *(const bf16x4*)(Vp + (size_t)(dt * 16 + r) * NS + kt + g * 4);
            bf16x4 v1 = *(const bf16x4*)(Vp + (size_t)(dt * 16 + r) * NS + kt + 16 + g * 4);
            vf[dt][0] = v0[0]; vf[dt][1] = v0[1]; vf[dt][2] = v0[2]; vf[dt][3] = v0[3];
            vf[dt][4] = v1[0]; vf[dt][5] = v1[1]; vf[dt][6] = v1[2]; vf[dt][7] = v1[3];
        }

#pragma unroll
        for (int qh = 0; qh < 2; qh++) {
            f32x4 T0 = (f32x4){0.f, 0.f, 0.f, 0.f};
            f32x4 T1 = (f32x4){0.f, 0.f, 0.f, 0.f};
            T0 = __builtin_amdgcn_mfma_f32_16x16x32_bf16(k00, qf[qh][0], T0, 0, 0, 0);
            T0 = __builtin_amdgcn_mfma_f32_16x16x32_bf16(k01, qf[qh][1], T0, 0, 0, 0);
            T1 = __builtin_amdgcn_mfma_f32_16x16x32_bf16(k10, qf[qh][0], T1, 0, 0, 0);
            T1 = __builtin_amdgcn_mfma_f32_16x16x32_bf16(k11, qf[qh][1], T1, 0, 0, 0);

            float p0[4], p1[4];
#pragma unroll
            for (int i = 0; i < 4; i++) {
                p0[i] = __expf(T0[i] * 0.125f);
                p1[i] = __expf(T1[i] * 0.125f);
                rsum[qh] += p0[i] + p1[i];
            }
            bf16x8 pf;
            pf[0] = f2bf(p0[0]); pf[1] = f2bf(p0[1]); pf[2] = f2bf(p0[2]); pf[3] = f2bf(p0[3]);
            pf[4] = f2bf(p1[0]); pf[5] = f2bf(p1[1]); pf[6] = f2bf(p1[2]); pf[7] = f2bf(p1[3]);
#pragma unroll
            for (int dt = 0; dt < 4; dt++)
                acc[qh][dt] = __builtin_amdgcn_mfma_f32_16x16x32_bf16(vf[dt], pf, acc[qh][dt], 0, 0, 0);
        }
    }

    // per-(wave,q) denominators: lane g-groups hold disjoint k partials
#pragma unroll
    for (int qh = 0; qh < 2; qh++) {
        rsum[qh] += __shfl_xor(rsum[qh], 16);
        rsum[qh] += __shfl_xor(rsum[qh], 32);
    }
    if (g == 0) {
        redsum[w][r]      = rsum[0];
        redsum[w][16 + r] = rsum[1];
    }
    // partial ctx^T -> LDS  (red[w][q][d])
#pragma unroll
    for (int qh = 0; qh < 2; qh++)
#pragma unroll
        for (int dt = 0; dt < 4; dt++)
#pragma unroll
            for (int i = 0; i < 4; i++)
                red[w][16 * qh + r][dt * 16 + g * 4 + i] = acc[qh][dt][i];
    __syncthreads();

    // combine 4 key-split partials, normalize, write bf16
    const int q  = tid >> 3;          // 0..31
    const int db = (tid & 7) * 8;     // 0,8,..,56
    const float inv = 1.0f / (redsum[0][q] + redsum[1][q] + redsum[2][q] + redsum[3][q]);
    bf16x8 outv;
#pragma unroll
    for (int j = 0; j < 8; j++) {
        const float s = red[0][q][db + j] + red[1][q][db + j] +
                        red[2][q][db + j] + red[3][q][db + j];
        outv[j] = f2bf(s * inv);
    }
    const int b = bh >> 4, h = bh & 15;
    *(bf16x8*)(Ctx + ((size_t)b * NS + qb + q) * ND + h * HD + db) = outv;
}

// ---------------------------------------------------------------------------
extern "C" void kernel_launch(void* const* d_in, const int* in_sizes, int n_in,
                              void* d_out, int out_size, void* d_ws, size_t ws_size,
                              hipStream_t stream) {
    (void)in_sizes; (void)n_in; (void)out_size; (void)ws_size;
    const float* query = (const float*)d_in[0];
    const float* key_  = (const float*)d_in[1];
    const float* value = (const float*)d_in[2];
    const float* Wq = (const float*)d_in[3];
    const float* bq = (const float*)d_in[4];
    const float* Wk = (const float*)d_in[5];
    const float* bk = (const float*)d_in[6];
    const float* Wv = (const float*)d_in[7];
    const float* bv = (const float*)d_in[8];
    const float* Wo = (const float*)d_in[9];
    const float* bo = (const float*)d_in[10];

    // ws layout (bytes): Wt x4 @0 (8 MiB), Q @8M, K @16M, Vt @24M, Ctx @32M  (40 MiB)
    char* ws = (char*)d_ws;
    short* WtAll = (short*)ws;
    short* Qb  = (short*)(ws + (size_t)8 * 1024 * 1024);
    short* Kb  = (short*)(ws + (size_t)16 * 1024 * 1024);
    short* Vtb = (short*)(ws + (size_t)24 * 1024 * 1024);
    short* Ctx = (short*)(ws + (size_t)32 * 1024 * 1024);

    prep_wt<<<dim3(32, 32, 4), 256, 0, stream>>>(Wq, Wk, Wv, Wo, WtAll);
    gemm_kern<0><<<dim3(32, 8), 256, 0, stream>>>(query, WtAll,                bq, Qb);
    gemm_kern<0><<<dim3(32, 8), 256, 0, stream>>>(key_,  WtAll + 1 * ND * ND,  bk, Kb);
    gemm_kern<1><<<dim3(32, 8), 256, 0, stream>>>(value, WtAll + 2 * ND * ND,  bv, Vtb);
    attn_kern<<<dim3(64, 32), 256, 0, stream>>>(Qb, Kb, Vtb, Ctx);
    gemm_kern<3><<<dim3(32, 8), 256, 0, stream>>>(Ctx, WtAll + 3 * ND * ND, bo, d_out);
}

// Round 3
// 147.805 us; speedup vs baseline: 3.3282x; 2.2291x over previous
//
#include <hip/hip_runtime.h>
#include <hip/hip_bf16.h>
#include <stdint.h>

// B=2, S=2048, D=1024, H=16, HD=64.
// KL bias = per-row constant -> softmax-invariant -> dropped.
// out = softmax(QK^T/8) V with 4 dense projections. bf16 MFMA, fp32 accum.
// Q is pre-scaled by log2(e)/8 so softmax is exp2().

#define NB 2
#define NS 2048
#define ND 1024
#define NH 16
#define HD 64

typedef short bf16x8 __attribute__((ext_vector_type(8)));
typedef short bf16x4 __attribute__((ext_vector_type(4)));
typedef float f32x4 __attribute__((ext_vector_type(4)));
typedef unsigned int u32x4 __attribute__((ext_vector_type(4)));

static __device__ __forceinline__ short f2bf(float f) {
    uint32_t u = __builtin_bit_cast(uint32_t, f);
    uint32_t r = (u + 0x7fffu + ((u >> 16) & 1u)) >> 16;
    return (short)(uint16_t)r;
}

static __device__ __forceinline__ unsigned int cvtpk(float lo, float hi) {
    unsigned int r;
    asm("v_cvt_pk_bf16_f32 %0, %1, %2" : "=v"(r) : "v"(lo), "v"(hi));
    return r;
}

typedef __attribute__((address_space(1))) const unsigned int glob_u32;
typedef __attribute__((address_space(3))) unsigned int lds_u32;
static __device__ __forceinline__ void gload16(const void* g, void* l) {
    __builtin_amdgcn_global_load_lds((glob_u32*)g, (lds_u32*)l, 16, 0, 0);
}

// ---------------------------------------------------------------------------
// prep_cast: fp32 -> bf16 for query/key/value (z picks tensor). 8 elems/thread.
// ---------------------------------------------------------------------------
__global__ __launch_bounds__(256) void prep_cast(const float* __restrict__ q,
                                                 const float* __restrict__ k,
                                                 const float* __restrict__ v,
                                                 short* __restrict__ Qo,
                                                 short* __restrict__ Ko,
                                                 short* __restrict__ Vo) {
    const float* src = (blockIdx.z == 0) ? q : (blockIdx.z == 1) ? k : v;
    short* dst = (blockIdx.z == 0) ? Qo : (blockIdx.z == 1) ? Ko : Vo;
    const size_t i = ((size_t)blockIdx.x * 256 + threadIdx.x) * 8;
    f32x4 a = *(const f32x4*)(src + i);
    f32x4 b = *(const f32x4*)(src + i + 4);
    bf16x8 o;
    o[0] = f2bf(a[0]); o[1] = f2bf(a[1]); o[2] = f2bf(a[2]); o[3] = f2bf(a[3]);
    o[4] = f2bf(b[0]); o[5] = f2bf(b[1]); o[6] = f2bf(b[2]); o[7] = f2bf(b[3]);
    *(bf16x8*)(dst + i) = o;
}

// ---------------------------------------------------------------------------
// prep_wt: Wt[n][k] = bf16(W[k][n]) for the 4 weight matrices (z = which).
// ---------------------------------------------------------------------------
__global__ __launch_bounds__(256) void prep_wt(const float* __restrict__ W0,
                                               const float* __restrict__ W1,
                                               const float* __restrict__ W2,
                                               const float* __restrict__ W3,
                                               short* __restrict__ WtAll) {
    __shared__ short tile[32][33];
    const float* W = (blockIdx.z == 0) ? W0 : (blockIdx.z == 1) ? W1
                   : (blockIdx.z == 2) ? W2 : W3;
    short* Wt = WtAll + (size_t)blockIdx.z * (ND * ND);
    const int tx = threadIdx.x & 31;
    const int ty = threadIdx.x >> 5;
    const int k0 = blockIdx.x * 32, n0 = blockIdx.y * 32;
#pragma unroll
    for (int i = 0; i < 4; i++)
        tile[ty + i * 8][tx] = f2bf(W[(size_t)(k0 + ty + i * 8) * ND + n0 + tx]);
    __syncthreads();
#pragma unroll
    for (int i = 0; i < 4; i++)
        Wt[(size_t)(n0 + ty + i * 8) * ND + k0 + tx] = tile[tx][ty + i * 8];
}

// ---------------------------------------------------------------------------
// Shared GEMM body (m97 structure): 128x128 tile, BK=32, global_load_lds
// staging (linear LDS [128][32]), 4 waves x 16 MFMA/step.
// A bf16 [4096][1024]; Wt bf16 [n][k]. mode: 0 bf16 [b][h][s][hd] (*scale),
// 1 bf16 [b][h][hd][s], 2 fp32 row-major.
// ---------------------------------------------------------------------------
static __device__ __forceinline__ void gemm_body(const short* __restrict__ A,
                                                 const short* __restrict__ Wt,
                                                 const float* __restrict__ bias,
                                                 void* __restrict__ Out,
                                                 int mode, float scale,
                                                 short* As, short* Bs) {
    const int tid = threadIdx.x;
    const int gm = blockIdx.x * 128;
    const int gn = blockIdx.y * 128;
    const int w = tid >> 6;
    const int l = tid & 63;
    const int r = l & 15;
    const int g = l >> 4;
    const int wr = w >> 1, wc = w & 1;

    f32x4 acc[4][4];
#pragma unroll
    for (int m = 0; m < 4; m++)
#pragma unroll
        for (int n = 0; n < 4; n++) acc[m][n] = (f32x4){0.f, 0.f, 0.f, 0.f};

    for (int k0 = 0; k0 < ND; k0 += 32) {
#pragma unroll
        for (int j = 0; j < 2; j++) {
            const int lin = ((w * 2 + j) << 10) + l * 16;  // byte in 8KB tile
            const int row = lin >> 6;                      // 64B rows
            const int cb = lin & 63;
            gload16((const char*)A + ((size_t)(gm + row) * ND + k0) * 2 + cb,
                    (char*)As + ((w * 2 + j) << 10));
            gload16((const char*)Wt + ((size_t)(gn + row) * ND + k0) * 2 + cb,
                    (char*)Bs + ((w * 2 + j) << 10));
        }
        __syncthreads();

        bf16x8 af[4], bfv[4];
#pragma unroll
        for (int m = 0; m < 4; m++)
            af[m] = *(const bf16x8*)((const char*)As + (wr * 64 + m * 16 + r) * 64 + g * 16);
#pragma unroll
        for (int n = 0; n < 4; n++)
            bfv[n] = *(const bf16x8*)((const char*)Bs + (wc * 64 + n * 16 + r) * 64 + g * 16);
#pragma unroll
        for (int m = 0; m < 4; m++)
#pragma unroll
            for (int n = 0; n < 4; n++)
                acc[m][n] = __builtin_amdgcn_mfma_f32_16x16x32_bf16(
                    af[m], bfv[n], acc[m][n], 0, 0, 0);
        __syncthreads();
    }

    // epilogue. C/D: reg i of lane -> row 4g+i, col r (round-1/2 verified)
#pragma unroll
    for (int m = 0; m < 4; m++) {
        const int orow = gm + wr * 64 + m * 16 + g * 4;
#pragma unroll
        for (int n = 0; n < 4; n++) {
            const int ocol = gn + wc * 64 + n * 16 + r;
            const float bv = bias[ocol];
#pragma unroll
            for (int i = 0; i < 4; i++) {
                const float vout = (acc[m][n][i] + bv) * scale;
                const int row = orow + i;
                if (mode == 0) {
                    const int b = row >> 11, s = row & 2047;
                    const int h = ocol >> 6, hd = ocol & 63;
                    ((short*)Out)[(((size_t)(b * NH + h) * NS + s) << 6) + hd] = f2bf(vout);
                } else if (mode == 1) {
                    const int b = row >> 11, s = row & 2047;
                    const int h = ocol >> 6, hd = ocol & 63;
                    ((short*)Out)[((size_t)(b * NH + h) * HD + hd) * NS + s] = f2bf(vout);
                } else {
                    ((float*)Out)[(size_t)row * ND + ocol] = vout;
                }
            }
        }
    }
}

#define QSCALE 0.18033688011112042f  // log2(e)/8

__global__ __launch_bounds__(256, 3) void gemm_qkv(const short* __restrict__ Qin,
                                                   const short* __restrict__ Kin,
                                                   const short* __restrict__ Vin,
                                                   const short* __restrict__ WtAll,
                                                   const float* __restrict__ bq,
                                                   const float* __restrict__ bk,
                                                   const float* __restrict__ bv,
                                                   short* __restrict__ Qo,
                                                   short* __restrict__ Ko,
                                                   short* __restrict__ Vto) {
    __shared__ __align__(16) short As[128 * 32];
    __shared__ __align__(16) short Bs[128 * 32];
    const int z = blockIdx.z;
    const short* A = (z == 0) ? Qin : (z == 1) ? Kin : Vin;
    const short* Wt = WtAll + (size_t)z * ND * ND;
    const float* bias = (z == 0) ? bq : (z == 1) ? bk : bv;
    void* Out = (z == 0) ? (void*)Qo : (z == 1) ? (void*)Ko : (void*)Vto;
    const float scale = (z == 0) ? QSCALE : 1.0f;
    const int mode = (z == 2) ? 1 : 0;
    gemm_body(A, Wt, bias, Out, mode, scale, As, Bs);
}

__global__ __launch_bounds__(256, 3) void gemm_fin(const short* __restrict__ Ctx,
                                                   const short* __restrict__ Wt,
                                                   const float* __restrict__ bo,
                                                   float* __restrict__ Out) {
    __shared__ __align__(16) short As[128 * 32];
    __shared__ __align__(16) short Bs[128 * 32];
    gemm_body(Ctx, Wt, bo, Out, 2, 1.0f, As, Bs);
}

// ---------------------------------------------------------------------------
// Attention v3: 512 blocks (XCD-swizzled), 4 waves/block, wave owns 32 q rows
// (2x16 halves). K/V staged in LDS, KVBLK=64, double-buffered 2-phase.
// XOR swizzle ((row&7)<<4 on byte addr) applied to BOTH gload source and
// ds_read addresses. Un-normalized single-pass softmax via exp2 (Q pre-scaled).
// ---------------------------------------------------------------------------
static __device__ __forceinline__ void stage_kv(const char* Kp8, const char* Vp8,
                                                short* KsB, short* VsB,
                                                int kt, int w, int l) {
#pragma unroll
    for (int j = 0; j < 2; j++) {
        const int lin = ((w * 2 + j) << 10) + l * 16;
        const int sw = lin ^ (((lin >> 7) & 7) << 4);
        gload16(Kp8 + (size_t)kt * 128 + sw, (char*)KsB + ((w * 2 + j) << 10));
        const int row = sw >> 7, col = sw & 127;
        gload16(Vp8 + (size_t)row * (NS * 2) + kt * 2 + col,
                (char*)VsB + ((w * 2 + j) << 10));
    }
}

__global__ __launch_bounds__(256, 2) void attn_kern(const short* __restrict__ Q,
                                                    const short* __restrict__ K,
                                                    const short* __restrict__ Vt,
                                                    short* __restrict__ Ctx) {
    __shared__ __align__(16) short Ks[2][64 * 64];
    __shared__ __align__(16) short Vs[2][64 * 64];

    const int tid = threadIdx.x;
    const int w = tid >> 6;
    const int l = tid & 63;
    const int r = l & 15;
    const int g = l >> 4;

    // XCD swizzle: 16 q-tiles of each bh cluster on one XCD (512 % 8 == 0)
    const int bid = blockIdx.x;
    const int swb = (bid & 7) * 64 + (bid >> 3);
    const int bh = swb >> 4;
    const int qt = swb & 15;
    const int qb = qt * 128 + w * 32;   // this wave's q base

    const short* Qp = Q + (size_t)bh * NS * HD;
    const char* Kp8 = (const char*)(K + (size_t)bh * NS * HD);
    const char* Vp8 = (const char*)(Vt + (size_t)bh * HD * NS);

    // Q fragments (B operand): qf[qh][c] = Q[qb+16qh+r][c*32 + 8g .. +7]
    bf16x8 qf[2][2];
#pragma unroll
    for (int qh = 0; qh < 2; qh++)
#pragma unroll
        for (int c = 0; c < 2; c++)
            qf[qh][c] = *(const bf16x8*)(Qp + (size_t)(qb + 16 * qh + r) * HD + c * 32 + g * 8);

    f32x4 acc[2][4];
#pragma unroll
    for (int qh = 0; qh < 2; qh++)
#pragma unroll
        for (int dt = 0; dt < 4; dt++) acc[qh][dt] = (f32x4){0.f, 0.f, 0.f, 0.f};
    float rs[2] = {0.f, 0.f};

    stage_kv(Kp8, Vp8, Ks[0], Vs[0], 0, w, l);
    __syncthreads();

    int bf = 0;
    for (int t = 0; t < NS / 64; t++) {
        if (t < NS / 64 - 1)
            stage_kv(Kp8, Vp8, Ks[bf ^ 1], Vs[bf ^ 1], (t + 1) * 64, w, l);

        const char* KsB = (const char*)Ks[bf];
        const char* VsB = (const char*)Vs[bf];
        const int sx = (r & 7) << 4;

        // ---- QK^T: T[qh][kt4], k = kt4*16 + 4g + i, q = qb+16qh+r
        f32x4 T[2][4];
#pragma unroll
        for (int kt4 = 0; kt4 < 4; kt4++) {
            const int rb = (kt4 * 16 + r) << 7;
            bf16x8 kf0 = *(const bf16x8*)(KsB + ((rb + (g << 4)) ^ sx));
            bf16x8 kf1 = *(const bf16x8*)(KsB + ((rb + 64 + (g << 4)) ^ sx));
            f32x4 t0 = (f32x4){0.f, 0.f, 0.f, 0.f};
            t0 = __builtin_amdgcn_mfma_f32_16x16x32_bf16(kf0, qf[0][0], t0, 0, 0, 0);
            t0 = __builtin_amdgcn_mfma_f32_16x16x32_bf16(kf1, qf[0][1], t0, 0, 0, 0);
            T[0][kt4] = t0;
            f32x4 t1 = (f32x4){0.f, 0.f, 0.f, 0.f};
            t1 = __builtin_amdgcn_mfma_f32_16x16x32_bf16(kf0, qf[1][0], t1, 0, 0, 0);
            t1 = __builtin_amdgcn_mfma_f32_16x16x32_bf16(kf1, qf[1][1], t1, 0, 0, 0);
            T[1][kt4] = t1;
        }

        // ---- P = exp2(T) (Q pre-scaled by log2e/8); row-sums
#pragma unroll
        for (int qh = 0; qh < 2; qh++)
#pragma unroll
            for (int kt4 = 0; kt4 < 4; kt4++) {
                f32x4 t = T[qh][kt4];
                t[0] = exp2f(t[0]); t[1] = exp2f(t[1]);
                t[2] = exp2f(t[2]); t[3] = exp2f(t[3]);
                T[qh][kt4] = t;
                rs[qh] += t[0] + t[1] + t[2] + t[3];
            }

        // ---- pack P -> bf16 fragments (k-permutation pi: j<4 -> 4g+j, j>=4 -> +16)
        bf16x8 pf[2][2];
#pragma unroll
        for (int qh = 0; qh < 2; qh++) {
            u32x4 p0, p1;
            p0[0] = cvtpk(T[qh][0][0], T[qh][0][1]);
            p0[1] = cvtpk(T[qh][0][2], T[qh][0][3]);
            p0[2] = cvtpk(T[qh][1][0], T[qh][1][1]);
            p0[3] = cvtpk(T[qh][1][2], T[qh][1][3]);
            p1[0] = cvtpk(T[qh][2][0], T[qh][2][1]);
            p1[1] = cvtpk(T[qh][2][2], T[qh][2][3]);
            p1[2] = cvtpk(T[qh][3][0], T[qh][3][1]);
            p1[3] = cvtpk(T[qh][3][2], T[qh][3][3]);
            pf[qh][0] = __builtin_bit_cast(bf16x8, p0);
            pf[qh][1] = __builtin_bit_cast(bf16x8, p1);
        }

        // ---- PV: A = V rows (d), same pi on k
#pragma unroll
        for (int dt = 0; dt < 4; dt++) {
            const int rb = (dt * 16 + r) << 7;
            bf16x4 a00 = *(const bf16x4*)(VsB + ((rb + (g << 3)) ^ sx));
            bf16x4 a01 = *(const bf16x4*)(VsB + ((rb + 32 + (g << 3)) ^ sx));
            bf16x4 a10 = *(const bf16x4*)(VsB + ((rb + 64 + (g << 3)) ^ sx));
            bf16x4 a11 = *(const bf16x4*)(VsB + ((rb + 96 + (g << 3)) ^ sx));
            bf16x8 vf0, vf1;
#pragma unroll
            for (int j = 0; j < 4; j++) {
                vf0[j] = a00[j]; vf0[4 + j] = a01[j];
                vf1[j] = a10[j]; vf1[4 + j] = a11[j];
            }
            acc[0][dt] = __builtin_amdgcn_mfma_f32_16x16x32_bf16(vf0, pf[0][0], acc[0][dt], 0, 0, 0);
            acc[0][dt] = __builtin_amdgcn_mfma_f32_16x16x32_bf16(vf1, pf[0][1], acc[0][dt], 0, 0, 0);
            acc[1][dt] = __builtin_amdgcn_mfma_f32_16x16x32_bf16(vf0, pf[1][0], acc[1][dt], 0, 0, 0);
            acc[1][dt] = __builtin_amdgcn_mfma_f32_16x16x32_bf16(vf1, pf[1][1], acc[1][dt], 0, 0, 0);
        }

        __syncthreads();
        bf ^= 1;
    }

    // denominators: sum over g groups
#pragma unroll
    for (int qh = 0; qh < 2; qh++) {
        rs[qh] += __shfl_xor(rs[qh], 16);
        rs[qh] += __shfl_xor(rs[qh], 32);
    }

    const int b = bh >> 4, h = bh & 15;
#pragma unroll
    for (int qh = 0; qh < 2; qh++) {
        const float inv = 1.0f / rs[qh];
        const int qrow = qb + qh * 16 + r;
#pragma unroll
        for (int dt = 0; dt < 4; dt++) {
            bf16x4 o;
#pragma unroll
            for (int i = 0; i < 4; i++) o[i] = f2bf(acc[qh][dt][i] * inv);
            *(bf16x4*)(Ctx + ((size_t)b * NS + qrow) * ND + h * HD + dt * 16 + g * 4) = o;
        }
    }
}

// ---------------------------------------------------------------------------
extern "C" void kernel_launch(void* const* d_in, const int* in_sizes, int n_in,
                              void* d_out, int out_size, void* d_ws, size_t ws_size,
                              hipStream_t stream) {
    (void)in_sizes; (void)n_in; (void)out_size; (void)ws_size;
    const float* query = (const float*)d_in[0];
    const float* key_  = (const float*)d_in[1];
    const float* value = (const float*)d_in[2];
    const float* Wq = (const float*)d_in[3];
    const float* bq = (const float*)d_in[4];
    const float* Wk = (const float*)d_in[5];
    const float* bk = (const float*)d_in[6];
    const float* Wv = (const float*)d_in[7];
    const float* bv = (const float*)d_in[8];
    const float* Wo = (const float*)d_in[9];
    const float* bo = (const float*)d_in[10];

    // ws (bytes): WtAll@0 (8M), Qin@8M, Kin@16M, Vin@24M, Qb@32M, Kb@40M,
    // Vtb@48M, Ctx@8M (reuses Qin after gemm_qkv).  Total 56 MiB.
    char* ws = (char*)d_ws;
    const size_t MB = 1024 * 1024;
    short* WtAll = (short*)ws;
    short* Qin = (short*)(ws + 8 * MB);
    short* Kin = (short*)(ws + 16 * MB);
    short* Vin = (short*)(ws + 24 * MB);
    short* Qb  = (short*)(ws + 32 * MB);
    short* Kb  = (short*)(ws + 40 * MB);
    short* Vtb = (short*)(ws + 48 * MB);
    short* Ctx = (short*)(ws + 8 * MB);   // reuse Qin

    prep_cast<<<dim3(2048, 1, 3), 256, 0, stream>>>(query, key_, value, Qin, Kin, Vin);
    prep_wt<<<dim3(32, 32, 4), 256, 0, stream>>>(Wq, Wk, Wv, Wo, WtAll);
    gemm_qkv<<<dim3(32, 8, 3), 256, 0, stream>>>(Qin, Kin, Vin, WtAll, bq, bk, bv,
                                                 Qb, Kb, Vtb);
    attn_kern<<<dim3(512), 256, 0, stream>>>(Qb, Kb, Vtb, Ctx);
    gemm_fin<<<dim3(32, 8), 256, 0, stream>>>(Ctx, WtAll + 3 * ND * ND, bo, (float*)d_out);
}

// Round 4
// 119.310 us; speedup vs baseline: 4.1231x; 1.2388x over previous
//
#include <hip/hip_runtime.h>
#include <hip/hip_bf16.h>
#include <stdint.h>

// B=2, S=2048, D=1024, H=16, HD=64.
// KL bias = per-row constant -> softmax-invariant -> dropped.
// out = softmax(QK^T/8) V with 4 dense projections. bf16 MFMA, fp32 accum.
// Q pre-scaled by log2(e)/8 so softmax is exp2().

#define NB 2
#define NS 2048
#define ND 1024
#define NH 16
#define HD 64

typedef short bf16x8 __attribute__((ext_vector_type(8)));
typedef short bf16x4 __attribute__((ext_vector_type(4)));
typedef float f32x4 __attribute__((ext_vector_type(4)));
typedef float f32x16 __attribute__((ext_vector_type(16)));
typedef unsigned int u32x4 __attribute__((ext_vector_type(4)));

static __device__ __forceinline__ short f2bf(float f) {
    uint32_t u = __builtin_bit_cast(uint32_t, f);
    uint32_t r = (u + 0x7fffu + ((u >> 16) & 1u)) >> 16;
    return (short)(uint16_t)r;
}

static __device__ __forceinline__ unsigned int cvtpk(float lo, float hi) {
    unsigned int r;
    asm("v_cvt_pk_bf16_f32 %0, %1, %2" : "=v"(r) : "v"(lo), "v"(hi));
    return r;
}

#if __has_builtin(__builtin_amdgcn_exp2f)
#define EXP2(x) __builtin_amdgcn_exp2f(x)
#else
#define EXP2(x) exp2f(x)
#endif

// after plswap(a,b): a = [a_lo | b_lo], b = [a_hi | b_hi]  (lane halves)
static __device__ __forceinline__ void plswap(unsigned& a, unsigned& b) {
#if __has_builtin(__builtin_amdgcn_permlane32_swap)
    auto r = __builtin_amdgcn_permlane32_swap(a, b, false, false);
    a = r[0]; b = r[1];
#else
    const int l = (int)(threadIdx.x & 63);
    unsigned bl = __shfl(b, l & 31);
    unsigned ah = __shfl(a, (l & 31) + 32);
    a = (l < 32) ? a : bl;
    b = (l < 32) ? ah : b;
#endif
}

typedef __attribute__((address_space(1))) const unsigned int glob_u32;
typedef __attribute__((address_space(3))) unsigned int lds_u32;
static __device__ __forceinline__ void gload16(const void* g, void* l) {
    __builtin_amdgcn_global_load_lds((glob_u32*)g, (lds_u32*)l, 16, 0, 0);
}

// ---------------------------------------------------------------------------
// prep_cast: fp32 -> bf16 for query/key/value (z picks tensor).
// ---------------------------------------------------------------------------
__global__ __launch_bounds__(256) void prep_cast(const float* __restrict__ q,
                                                 const float* __restrict__ k,
                                                 const float* __restrict__ v,
                                                 short* __restrict__ Qo,
                                                 short* __restrict__ Ko,
                                                 short* __restrict__ Vo) {
    const float* src = (blockIdx.z == 0) ? q : (blockIdx.z == 1) ? k : v;
    short* dst = (blockIdx.z == 0) ? Qo : (blockIdx.z == 1) ? Ko : Vo;
    const size_t i = ((size_t)blockIdx.x * 256 + threadIdx.x) * 8;
    f32x4 a = *(const f32x4*)(src + i);
    f32x4 b = *(const f32x4*)(src + i + 4);
    bf16x8 o;
    o[0] = f2bf(a[0]); o[1] = f2bf(a[1]); o[2] = f2bf(a[2]); o[3] = f2bf(a[3]);
    o[4] = f2bf(b[0]); o[5] = f2bf(b[1]); o[6] = f2bf(b[2]); o[7] = f2bf(b[3]);
    *(bf16x8*)(dst + i) = o;
}

// ---------------------------------------------------------------------------
// prep_wt: Wt[n][k] = bf16(W[k][n]) for the 4 weight matrices (z = which).
// ---------------------------------------------------------------------------
__global__ __launch_bounds__(256) void prep_wt(const float* __restrict__ W0,
                                               const float* __restrict__ W1,
                                               const float* __restrict__ W2,
                                               const float* __restrict__ W3,
                                               short* __restrict__ WtAll) {
    __shared__ short tile[32][33];
    const float* W = (blockIdx.z == 0) ? W0 : (blockIdx.z == 1) ? W1
                   : (blockIdx.z == 2) ? W2 : W3;
    short* Wt = WtAll + (size_t)blockIdx.z * (ND * ND);
    const int tx = threadIdx.x & 31;
    const int ty = threadIdx.x >> 5;
    const int k0 = blockIdx.x * 32, n0 = blockIdx.y * 32;
#pragma unroll
    for (int i = 0; i < 4; i++)
        tile[ty + i * 8][tx] = f2bf(W[(size_t)(k0 + ty + i * 8) * ND + n0 + tx]);
    __syncthreads();
#pragma unroll
    for (int i = 0; i < 4; i++)
        Wt[(size_t)(n0 + ty + i * 8) * ND + k0 + tx] = tile[tx][ty + i * 8];
}

// ---------------------------------------------------------------------------
// Shared GEMM body (m97 structure): 128x128 tile, BK=32, global_load_lds.
// ---------------------------------------------------------------------------
static __device__ __forceinline__ void gemm_body(const short* __restrict__ A,
                                                 const short* __restrict__ Wt,
                                                 const float* __restrict__ bias,
                                                 void* __restrict__ Out,
                                                 int mode, float scale,
                                                 short* As, short* Bs) {
    const int tid = threadIdx.x;
    const int gm = blockIdx.x * 128;
    const int gn = blockIdx.y * 128;
    const int w = tid >> 6;
    const int l = tid & 63;
    const int r = l & 15;
    const int g = l >> 4;
    const int wr = w >> 1, wc = w & 1;

    f32x4 acc[4][4];
#pragma unroll
    for (int m = 0; m < 4; m++)
#pragma unroll
        for (int n = 0; n < 4; n++) acc[m][n] = (f32x4){0.f, 0.f, 0.f, 0.f};

    for (int k0 = 0; k0 < ND; k0 += 32) {
#pragma unroll
        for (int j = 0; j < 2; j++) {
            const int lin = ((w * 2 + j) << 10) + l * 16;
            const int row = lin >> 6;
            const int cb = lin & 63;
            gload16((const char*)A + ((size_t)(gm + row) * ND + k0) * 2 + cb,
                    (char*)As + ((w * 2 + j) << 10));
            gload16((const char*)Wt + ((size_t)(gn + row) * ND + k0) * 2 + cb,
                    (char*)Bs + ((w * 2 + j) << 10));
        }
        __syncthreads();

        bf16x8 af[4], bfv[4];
#pragma unroll
        for (int m = 0; m < 4; m++)
            af[m] = *(const bf16x8*)((const char*)As + (wr * 64 + m * 16 + r) * 64 + g * 16);
#pragma unroll
        for (int n = 0; n < 4; n++)
            bfv[n] = *(const bf16x8*)((const char*)Bs + (wc * 64 + n * 16 + r) * 64 + g * 16);
#pragma unroll
        for (int m = 0; m < 4; m++)
#pragma unroll
            for (int n = 0; n < 4; n++)
                acc[m][n] = __builtin_amdgcn_mfma_f32_16x16x32_bf16(
                    af[m], bfv[n], acc[m][n], 0, 0, 0);
        __syncthreads();
    }

#pragma unroll
    for (int m = 0; m < 4; m++) {
        const int orow = gm + wr * 64 + m * 16 + g * 4;
#pragma unroll
        for (int n = 0; n < 4; n++) {
            const int ocol = gn + wc * 64 + n * 16 + r;
            const float bv = bias[ocol];
#pragma unroll
            for (int i = 0; i < 4; i++) {
                const float vout = (acc[m][n][i] + bv) * scale;
                const int row = orow + i;
                if (mode == 0) {
                    const int b = row >> 11, s = row & 2047;
                    const int h = ocol >> 6, hd = ocol & 63;
                    ((short*)Out)[(((size_t)(b * NH + h) * NS + s) << 6) + hd] = f2bf(vout);
                } else if (mode == 1) {
                    const int b = row >> 11, s = row & 2047;
                    const int h = ocol >> 6, hd = ocol & 63;
                    ((short*)Out)[((size_t)(b * NH + h) * HD + hd) * NS + s] = f2bf(vout);
                } else {
                    ((float*)Out)[(size_t)row * ND + ocol] = vout;
                }
            }
        }
    }
}

#define QSCALE 0.18033688011112042f  // log2(e)/8

__global__ __launch_bounds__(256, 3) void gemm_qkv(const short* __restrict__ Qin,
                                                   const short* __restrict__ Kin,
                                                   const short* __restrict__ Vin,
                                                   const short* __restrict__ WtAll,
                                                   const float* __restrict__ bq,
                                                   const float* __restrict__ bk,
                                                   const float* __restrict__ bv,
                                                   short* __restrict__ Qo,
                                                   short* __restrict__ Ko,
                                                   short* __restrict__ Vto) {
    __shared__ __align__(16) short As[128 * 32];
    __shared__ __align__(16) short Bs[128 * 32];
    const int z = blockIdx.z;
    const short* A = (z == 0) ? Qin : (z == 1) ? Kin : Vin;
    const short* Wt = WtAll + (size_t)z * ND * ND;
    const float* bias = (z == 0) ? bq : (z == 1) ? bk : bv;
    void* Out = (z == 0) ? (void*)Qo : (z == 1) ? (void*)Ko : (void*)Vto;
    const float scale = (z == 0) ? QSCALE : 1.0f;
    const int mode = (z == 2) ? 1 : 0;
    gemm_body(A, Wt, bias, Out, mode, scale, As, Bs);
}

__global__ __launch_bounds__(256, 3) void gemm_fin(const short* __restrict__ Ctx,
                                                   const short* __restrict__ Wt,
                                                   const float* __restrict__ bo,
                                                   float* __restrict__ Out) {
    __shared__ __align__(16) short As[128 * 32];
    __shared__ __align__(16) short Bs[128 * 32];
    gemm_body(Ctx, Wt, bo, Out, 2, 1.0f, As, Bs);
}

// ---------------------------------------------------------------------------
// Attention v4: 512 blocks x 512 threads. Block owns 128 q rows of one (b,h).
// Waves 0-3: keys 0..1023; waves 4-7: keys 1024..2047 (linear merge via LDS).
// Wave w and w+4 share q rows [qt*128 + (w&3)*32, +32).
// 32x32x16 MFMA. S^T = K·Q^T; P rearranged to PV A-fragment with 2
// permlane32_swap per 16-k step; V consumed as B operand via ds_read_b128
// from [d][key] LDS tile (XOR-swizzled both sides). Un-normalized softmax.
// K tile and V tile are each [64 rows][128 bytes], double-buffered (64 KiB).
// ---------------------------------------------------------------------------
static __device__ __forceinline__ void stage2(const char* Kp8, const char* Vp8,
                                              char* Kbuf, char* Vbuf,
                                              int t, int w, int l) {
#pragma unroll
    for (int jj = 0; jj < 2; jj++) {
        const int chunk = w * 2 + jj;                   // 0..15
        const int half = chunk >> 3;                    // key half
        const int lin = ((chunk & 7) << 10) + l * 16;   // 0..8191 in subtile
        const int sw = lin ^ (((lin >> 7) & 7) << 4);
        const int row = sw >> 7, col = sw & 127;
        gload16(Kp8 + (size_t)(half * 1024 + t * 64 + row) * 128 + col,
                Kbuf + half * 8192 + ((chunk & 7) << 10));
        gload16(Vp8 + (size_t)row * (NS * 2) + (half * 1024 + t * 64) * 2 + col,
                Vbuf + half * 8192 + ((chunk & 7) << 10));
    }
}

__global__ __launch_bounds__(512, 4) void attn_kern(const short* __restrict__ Q,
                                                    const short* __restrict__ K,
                                                    const short* __restrict__ Vt,
                                                    short* __restrict__ Ctx) {
    __shared__ __align__(16) char smem[2][2][16384];   // [buf][K/V][bytes]

    const int tid = threadIdx.x;
    const int w = tid >> 6;        // 0..7
    const int l = tid & 63;
    const int c = l & 31;
    const int h = l >> 5;
    const int h16 = h << 4;

    // XCD swizzle (512 % 8 == 0, bijective)
    const int bid = blockIdx.x;
    const int swb = (bid & 7) * 64 + (bid >> 3);
    const int bh = swb >> 4;
    const int qt = swb & 15;
    const int qb = qt * 128 + (w & 3) * 32;

    const short* Qp = Q + (size_t)bh * NS * HD;
    const char* Kp8 = (const char*)(K + (size_t)bh * NS * HD);
    const char* Vp8 = (const char*)(Vt + (size_t)bh * HD * NS);

    // Q fragments (B operand): slot (h,j) of step st <-> d = st*16 + 8h + j
    bf16x8 qf[4];
    {
        const short* Qrow = Qp + (size_t)(qb + c) * HD;
#pragma unroll
        for (int st = 0; st < 4; st++)
            qf[st] = *(const bf16x8*)(Qrow + st * 16 + h * 8);
    }

    f32x16 acc[2];
    acc[0] = (f32x16)(0.f);
    acc[1] = (f32x16)(0.f);
    float rsum = 0.f;

    const int khalf = w >> 2;
    const int sx = (c & 7) << 4;

    stage2(Kp8, Vp8, smem[0][0], smem[0][1], 0, w, l);
    __syncthreads();

    int bufi = 0;
    for (int t = 0; t < 16; t++) {
        if (t < 15)
            stage2(Kp8, Vp8, smem[bufi ^ 1][0], smem[bufi ^ 1][1], t + 1, w, l);

        const char* Kt = smem[bufi][0] + khalf * 8192;
        const char* Vv = smem[bufi][1] + khalf * 8192;

#pragma unroll
        for (int ktile = 0; ktile < 2; ktile++) {
            // ---- S^T = K·Q^T over d (4 steps of K=16)
            bf16x8 kf[4];
#pragma unroll
            for (int st = 0; st < 4; st++)
                kf[st] = *(const bf16x8*)(Kt + ((ktile * 32 + c) << 7) +
                                          ((st * 32 + h16) ^ sx));
            f32x16 S = (f32x16)(0.f);
#pragma unroll
            for (int st = 0; st < 4; st++)
                S = __builtin_amdgcn_mfma_f32_32x32x16_bf16(kf[st], qf[st], S, 0, 0, 0);

            // ---- P = exp2(S); lane reg q4*4+i -> k_local = i + 8*q4 + 4h, q = c
            float tv[16];
#pragma unroll
            for (int i = 0; i < 16; i++) { tv[i] = EXP2(S[i]); rsum += tv[i]; }

            unsigned v0[4], v1[4];
#pragma unroll
            for (int q4 = 0; q4 < 4; q4++) {
                v0[q4] = cvtpk(tv[4 * q4], tv[4 * q4 + 1]);
                v1[q4] = cvtpk(tv[4 * q4 + 2], tv[4 * q4 + 3]);
            }

            // ---- PV: two K=16 steps; P rearranged so slot (h,j) <-> k = 8h+j
#pragma unroll
            for (int ks = 0; ks < 2; ks++) {
                unsigned a0 = v0[2 * ks], b0 = v0[2 * ks + 1];
                unsigned a1 = v1[2 * ks], b1 = v1[2 * ks + 1];
                plswap(a0, b0);
                plswap(a1, b1);
                u32x4 paw; paw[0] = a0; paw[1] = a1; paw[2] = b0; paw[3] = b1;
                bf16x8 pa = __builtin_bit_cast(bf16x8, paw);
#pragma unroll
                for (int dt = 0; dt < 2; dt++) {
                    bf16x8 vb = *(const bf16x8*)(Vv + ((dt * 32 + c) << 7) +
                                                 ((ktile * 64 + ks * 32 + h16) ^ sx));
                    acc[dt] = __builtin_amdgcn_mfma_f32_32x32x16_bf16(pa, vb, acc[dt], 0, 0, 0);
                }
            }
        }
        __syncthreads();
        bufi ^= 1;
    }

    // ---- merge the two key halves; normalize; write
    rsum += __shfl_xor(rsum, 32);       // full per-q denominator of this key half

    float* rsbuf = (float*)&smem[0][0][0];        // [8][32]
    float* sumbuf = (float*)&smem[0][0][0] + 256; // [4][32][64]
    if (h == 0) rsbuf[w * 32 + c] = rsum;
    if (w >= 4) {
#pragma unroll
        for (int q4 = 0; q4 < 4; q4++)
#pragma unroll
            for (int i = 0; i < 4; i++) {
                const int qrow = i + 8 * q4 + 4 * h;
#pragma unroll
                for (int dt = 0; dt < 2; dt++)
                    sumbuf[(((w - 4) * 32 + qrow) << 6) + dt * 32 + c] = acc[dt][q4 * 4 + i];
            }
    }
    __syncthreads();
    if (w < 4) {
        const int b = bh >> 4, hh = bh & 15;
#pragma unroll
        for (int q4 = 0; q4 < 4; q4++)
#pragma unroll
            for (int i = 0; i < 4; i++) {
                const int qrow = i + 8 * q4 + 4 * h;
                const float inv = 1.0f / (rsbuf[w * 32 + qrow] + rsbuf[(w + 4) * 32 + qrow]);
                short* op = Ctx + ((size_t)b * NS + qb + qrow) * ND + hh * HD;
#pragma unroll
                for (int dt = 0; dt < 2; dt++) {
                    const float vsum = acc[dt][q4 * 4 + i] +
                                       sumbuf[((w * 32 + qrow) << 6) + dt * 32 + c];
                    op[dt * 32 + c] = f2bf(vsum * inv);
                }
            }
    }
}

// ---------------------------------------------------------------------------
extern "C" void kernel_launch(void* const* d_in, const int* in_sizes, int n_in,
                              void* d_out, int out_size, void* d_ws, size_t ws_size,
                              hipStream_t stream) {
    (void)in_sizes; (void)n_in; (void)out_size; (void)ws_size;
    const float* query = (const float*)d_in[0];
    const float* key_  = (const float*)d_in[1];
    const float* value = (const float*)d_in[2];
    const float* Wq = (const float*)d_in[3];
    const float* bq = (const float*)d_in[4];
    const float* Wk = (const float*)d_in[5];
    const float* bk = (const float*)d_in[6];
    const float* Wv = (const float*)d_in[7];
    const float* bv = (const float*)d_in[8];
    const float* Wo = (const float*)d_in[9];
    const float* bo = (const float*)d_in[10];

    char* ws = (char*)d_ws;
    const size_t MB = 1024 * 1024;
    short* WtAll = (short*)ws;
    short* Qin = (short*)(ws + 8 * MB);
    short* Kin = (short*)(ws + 16 * MB);
    short* Vin = (short*)(ws + 24 * MB);
    short* Qb  = (short*)(ws + 32 * MB);
    short* Kb  = (short*)(ws + 40 * MB);
    short* Vtb = (short*)(ws + 48 * MB);
    short* Ctx = (short*)(ws + 8 * MB);   // reuse Qin

    prep_cast<<<dim3(2048, 1, 3), 256, 0, stream>>>(query, key_, value, Qin, Kin, Vin);
    prep_wt<<<dim3(32, 32, 4), 256, 0, stream>>>(Wq, Wk, Wv, Wo, WtAll);
    gemm_qkv<<<dim3(32, 8, 3), 256, 0, stream>>>(Qin, Kin, Vin, WtAll, bq, bk, bv,
                                                 Qb, Kb, Vtb);
    attn_kern<<<dim3(512), 512, 0, stream>>>(Qb, Kb, Vtb, Ctx);
    gemm_fin<<<dim3(32, 8), 256, 0, stream>>>(Ctx, WtAll + 3 * ND * ND, bo, (float*)d_out);
}

// Round 5
// 119.107 us; speedup vs baseline: 4.1302x; 1.0017x over previous
//
#include <hip/hip_runtime.h>
#include <hip/hip_bf16.h>
#include <stdint.h>

// B=2, S=2048, D=1024, H=16, HD=64.
// KL bias = per-row constant -> softmax-invariant -> dropped.
// out = softmax(QK^T/8) V with 4 dense projections. bf16 MFMA, fp32 accum.
// Q pre-scaled by log2(e)/8 so softmax is exp2().

#define NB 2
#define NS 2048
#define ND 1024
#define NH 16
#define HD 64

typedef short bf16x8 __attribute__((ext_vector_type(8)));
typedef short bf16x4 __attribute__((ext_vector_type(4)));
typedef float f32x4 __attribute__((ext_vector_type(4)));
typedef float f32x16 __attribute__((ext_vector_type(16)));
typedef unsigned int u32x4 __attribute__((ext_vector_type(4)));

static __device__ __forceinline__ short f2bf(float f) {
    uint32_t u = __builtin_bit_cast(uint32_t, f);
    uint32_t r = (u + 0x7fffu + ((u >> 16) & 1u)) >> 16;
    return (short)(uint16_t)r;
}

static __device__ __forceinline__ unsigned int cvtpk(float lo, float hi) {
    unsigned int r;
    asm("v_cvt_pk_bf16_f32 %0, %1, %2" : "=v"(r) : "v"(lo), "v"(hi));
    return r;
}

#if __has_builtin(__builtin_amdgcn_exp2f)
#define EXP2(x) __builtin_amdgcn_exp2f(x)
#else
#define EXP2(x) exp2f(x)
#endif

// after plswap(a,b): a = [a_lo | b_lo], b = [a_hi | b_hi]  (lane halves)
static __device__ __forceinline__ void plswap(unsigned& a, unsigned& b) {
#if __has_builtin(__builtin_amdgcn_permlane32_swap)
    auto r = __builtin_amdgcn_permlane32_swap(a, b, false, false);
    a = r[0]; b = r[1];
#else
    const int l = (int)(threadIdx.x & 63);
    unsigned bl = __shfl(b, l & 31);
    unsigned ah = __shfl(a, (l & 31) + 32);
    a = (l < 32) ? a : bl;
    b = (l < 32) ? ah : b;
#endif
}

typedef __attribute__((address_space(1))) const unsigned int glob_u32;
typedef __attribute__((address_space(3))) unsigned int lds_u32;
static __device__ __forceinline__ void gload16(const void* g, void* l) {
    __builtin_amdgcn_global_load_lds((glob_u32*)g, (lds_u32*)l, 16, 0, 0);
}

// ---------------------------------------------------------------------------
// prep_cast: fp32 -> bf16 for query/key/value (z picks tensor).
// ---------------------------------------------------------------------------
__global__ __launch_bounds__(256) void prep_cast(const float* __restrict__ q,
                                                 const float* __restrict__ k,
                                                 const float* __restrict__ v,
                                                 short* __restrict__ Qo,
                                                 short* __restrict__ Ko,
                                                 short* __restrict__ Vo) {
    const float* src = (blockIdx.z == 0) ? q : (blockIdx.z == 1) ? k : v;
    short* dst = (blockIdx.z == 0) ? Qo : (blockIdx.z == 1) ? Ko : Vo;
    const size_t i = ((size_t)blockIdx.x * 256 + threadIdx.x) * 8;
    f32x4 a = *(const f32x4*)(src + i);
    f32x4 b = *(const f32x4*)(src + i + 4);
    bf16x8 o;
    o[0] = f2bf(a[0]); o[1] = f2bf(a[1]); o[2] = f2bf(a[2]); o[3] = f2bf(a[3]);
    o[4] = f2bf(b[0]); o[5] = f2bf(b[1]); o[6] = f2bf(b[2]); o[7] = f2bf(b[3]);
    *(bf16x8*)(dst + i) = o;
}

// ---------------------------------------------------------------------------
// prep_wt: Wt[n][k] = bf16(W[k][n]) for the 4 weight matrices (z = which).
// ---------------------------------------------------------------------------
__global__ __launch_bounds__(256) void prep_wt(const float* __restrict__ W0,
                                               const float* __restrict__ W1,
                                               const float* __restrict__ W2,
                                               const float* __restrict__ W3,
                                               short* __restrict__ WtAll) {
    __shared__ short tile[32][33];
    const float* W = (blockIdx.z == 0) ? W0 : (blockIdx.z == 1) ? W1
                   : (blockIdx.z == 2) ? W2 : W3;
    short* Wt = WtAll + (size_t)blockIdx.z * (ND * ND);
    const int tx = threadIdx.x & 31;
    const int ty = threadIdx.x >> 5;
    const int k0 = blockIdx.x * 32, n0 = blockIdx.y * 32;
#pragma unroll
    for (int i = 0; i < 4; i++)
        tile[ty + i * 8][tx] = f2bf(W[(size_t)(k0 + ty + i * 8) * ND + n0 + tx]);
    __syncthreads();
#pragma unroll
    for (int i = 0; i < 4; i++)
        Wt[(size_t)(n0 + ty + i * 8) * ND + k0 + tx] = tile[tx][ty + i * 8];
}

// ---------------------------------------------------------------------------
// Shared GEMM body: 128x128 tile, BK=32, global_load_lds staging,
// DOUBLE-buffered LDS (one barrier per K-step), both-sides XOR swizzle
// f(row) = ((row ^ row>>2) & 3) << 4 so fragment ds_read_b128 is
// bank-conflict-free (8 banks x 2-way).
// ---------------------------------------------------------------------------
static __device__ __forceinline__ void gemm_body(const short* __restrict__ A,
                                                 const short* __restrict__ Wt,
                                                 const float* __restrict__ bias,
                                                 void* __restrict__ Out,
                                                 int mode, float scale,
                                                 char* As2, char* Bs2) {
    const int tid = threadIdx.x;
    const int gm = blockIdx.x * 128;
    const int gn = blockIdx.y * 128;
    const int w = tid >> 6;
    const int l = tid & 63;
    const int r = l & 15;
    const int g = l >> 4;
    const int wr = w >> 1, wc = w & 1;

    f32x4 acc[4][4];
#pragma unroll
    for (int m = 0; m < 4; m++)
#pragma unroll
        for (int n = 0; n < 4; n++) acc[m][n] = (f32x4){0.f, 0.f, 0.f, 0.f};

    // per-thread staging constants
    const int lin = ((w * 2) << 10) + l * 16;      // chunk j=0; j=1 adds 1024
    // prologue: stage tile 0 into buffer 0
#pragma unroll
    for (int j = 0; j < 2; j++) {
        const int lj = lin + (j << 10);
        const int row = lj >> 6;
        const int colL = (lj & 63) ^ (((row ^ (row >> 2)) & 3) << 4);
        gload16((const char*)A + (size_t)(gm + row) * (ND * 2) + colL, As2 + lj);
        gload16((const char*)Wt + (size_t)(gn + row) * (ND * 2) + colL, Bs2 + lj);
    }
    __syncthreads();

    for (int t = 0; t < ND / 32; t++) {
        const int cur = (t & 1) << 13;   // 8192-byte buffers
        const int nxt = cur ^ 8192;
        if (t < ND / 32 - 1) {
            const int k0b = (t + 1) * 64;   // byte offset of K-slice
#pragma unroll
            for (int j = 0; j < 2; j++) {
                const int lj = lin + (j << 10);
                const int row = lj >> 6;
                const int colL = (lj & 63) ^ (((row ^ (row >> 2)) & 3) << 4);
                gload16((const char*)A + (size_t)(gm + row) * (ND * 2) + k0b + colL,
                        As2 + nxt + lj);
                gload16((const char*)Wt + (size_t)(gn + row) * (ND * 2) + k0b + colL,
                        Bs2 + nxt + lj);
            }
        }

        bf16x8 af[4], bfv[4];
#pragma unroll
        for (int m = 0; m < 4; m++) {
            const int ar = wr * 64 + m * 16 + r;
            const int fa = ((ar ^ (ar >> 2)) & 3) << 4;
            af[m] = *(const bf16x8*)(As2 + cur + ar * 64 + ((g << 4) ^ fa));
        }
#pragma unroll
        for (int n = 0; n < 4; n++) {
            const int br = wc * 64 + n * 16 + r;
            const int fb = ((br ^ (br >> 2)) & 3) << 4;
            bfv[n] = *(const bf16x8*)(Bs2 + cur + br * 64 + ((g << 4) ^ fb));
        }
#pragma unroll
        for (int m = 0; m < 4; m++)
#pragma unroll
            for (int n = 0; n < 4; n++)
                acc[m][n] = __builtin_amdgcn_mfma_f32_16x16x32_bf16(
                    af[m], bfv[n], acc[m][n], 0, 0, 0);
        __syncthreads();
    }

#pragma unroll
    for (int m = 0; m < 4; m++) {
        const int orow = gm + wr * 64 + m * 16 + g * 4;
#pragma unroll
        for (int n = 0; n < 4; n++) {
            const int ocol = gn + wc * 64 + n * 16 + r;
            const float bv = bias[ocol];
#pragma unroll
            for (int i = 0; i < 4; i++) {
                const float vout = (acc[m][n][i] + bv) * scale;
                const int row = orow + i;
                if (mode == 0) {
                    const int b = row >> 11, s = row & 2047;
                    const int h = ocol >> 6, hd = ocol & 63;
                    ((short*)Out)[(((size_t)(b * NH + h) * NS + s) << 6) + hd] = f2bf(vout);
                } else if (mode == 1) {
                    const int b = row >> 11, s = row & 2047;
                    const int h = ocol >> 6, hd = ocol & 63;
                    ((short*)Out)[((size_t)(b * NH + h) * HD + hd) * NS + s] = f2bf(vout);
                } else {
                    ((float*)Out)[(size_t)row * ND + ocol] = vout;
                }
            }
        }
    }
}

#define QSCALE 0.18033688011112042f  // log2(e)/8

__global__ __launch_bounds__(256, 3) void gemm_qkv(const short* __restrict__ Qin,
                                                   const short* __restrict__ Kin,
                                                   const short* __restrict__ Vin,
                                                   const short* __restrict__ WtAll,
                                                   const float* __restrict__ bq,
                                                   const float* __restrict__ bk,
                                                   const float* __restrict__ bv,
                                                   short* __restrict__ Qo,
                                                   short* __restrict__ Ko,
                                                   short* __restrict__ Vto) {
    __shared__ __align__(16) char As[2 * 8192];
    __shared__ __align__(16) char Bs[2 * 8192];
    const int z = blockIdx.z;
    const short* A = (z == 0) ? Qin : (z == 1) ? Kin : Vin;
    const short* Wt = WtAll + (size_t)z * ND * ND;
    const float* bias = (z == 0) ? bq : (z == 1) ? bk : bv;
    void* Out = (z == 0) ? (void*)Qo : (z == 1) ? (void*)Ko : (void*)Vto;
    const float scale = (z == 0) ? QSCALE : 1.0f;
    const int mode = (z == 2) ? 1 : 0;
    gemm_body(A, Wt, bias, Out, mode, scale, As, Bs);
}

__global__ __launch_bounds__(256, 3) void gemm_fin(const short* __restrict__ Ctx,
                                                   const short* __restrict__ Wt,
                                                   const float* __restrict__ bo,
                                                   float* __restrict__ Out) {
    __shared__ __align__(16) char As[2 * 8192];
    __shared__ __align__(16) char Bs[2 * 8192];
    gemm_body(Ctx, Wt, bo, Out, 2, 1.0f, As, Bs);
}

// ---------------------------------------------------------------------------
// Attention v4 (unchanged from round 4): 512 blocks x 512 threads.
// ---------------------------------------------------------------------------
static __device__ __forceinline__ void stage2(const char* Kp8, const char* Vp8,
                                              char* Kbuf, char* Vbuf,
                                              int t, int w, int l) {
#pragma unroll
    for (int jj = 0; jj < 2; jj++) {
        const int chunk = w * 2 + jj;                   // 0..15
        const int half = chunk >> 3;                    // key half
        const int lin = ((chunk & 7) << 10) + l * 16;   // 0..8191 in subtile
        const int sw = lin ^ (((lin >> 7) & 7) << 4);
        const int row = sw >> 7, col = sw & 127;
        gload16(Kp8 + (size_t)(half * 1024 + t * 64 + row) * 128 + col,
                Kbuf + half * 8192 + ((chunk & 7) << 10));
        gload16(Vp8 + (size_t)row * (NS * 2) + (half * 1024 + t * 64) * 2 + col,
                Vbuf + half * 8192 + ((chunk & 7) << 10));
    }
}

__global__ __launch_bounds__(512, 4) void attn_kern(const short* __restrict__ Q,
                                                    const short* __restrict__ K,
                                                    const short* __restrict__ Vt,
                                                    short* __restrict__ Ctx) {
    __shared__ __align__(16) char smem[2][2][16384];   // [buf][K/V][bytes]

    const int tid = threadIdx.x;
    const int w = tid >> 6;        // 0..7
    const int l = tid & 63;
    const int c = l & 31;
    const int h = l >> 5;
    const int h16 = h << 4;

    // XCD swizzle (512 % 8 == 0, bijective)
    const int bid = blockIdx.x;
    const int swb = (bid & 7) * 64 + (bid >> 3);
    const int bh = swb >> 4;
    const int qt = swb & 15;
    const int qb = qt * 128 + (w & 3) * 32;

    const short* Qp = Q + (size_t)bh * NS * HD;
    const char* Kp8 = (const char*)(K + (size_t)bh * NS * HD);
    const char* Vp8 = (const char*)(Vt + (size_t)bh * HD * NS);

    // Q fragments (B operand): slot (h,j) of step st <-> d = st*16 + 8h + j
    bf16x8 qf[4];
    {
        const short* Qrow = Qp + (size_t)(qb + c) * HD;
#pragma unroll
        for (int st = 0; st < 4; st++)
            qf[st] = *(const bf16x8*)(Qrow + st * 16 + h * 8);
    }

    f32x16 acc[2];
    acc[0] = (f32x16)(0.f);
    acc[1] = (f32x16)(0.f);
    float rsum = 0.f;

    const int khalf = w >> 2;
    const int sx = (c & 7) << 4;

    stage2(Kp8, Vp8, smem[0][0], smem[0][1], 0, w, l);
    __syncthreads();

    int bufi = 0;
    for (int t = 0; t < 16; t++) {
        if (t < 15)
            stage2(Kp8, Vp8, smem[bufi ^ 1][0], smem[bufi ^ 1][1], t + 1, w, l);

        const char* Kt = smem[bufi][0] + khalf * 8192;
        const char* Vv = smem[bufi][1] + khalf * 8192;

#pragma unroll
        for (int ktile = 0; ktile < 2; ktile++) {
            // ---- S^T = K·Q^T over d (4 steps of K=16)
            bf16x8 kf[4];
#pragma unroll
            for (int st = 0; st < 4; st++)
                kf[st] = *(const bf16x8*)(Kt + ((ktile * 32 + c) << 7) +
                                          ((st * 32 + h16) ^ sx));
            f32x16 S = (f32x16)(0.f);
#pragma unroll
            for (int st = 0; st < 4; st++)
                S = __builtin_amdgcn_mfma_f32_32x32x16_bf16(kf[st], qf[st], S, 0, 0, 0);

            // ---- P = exp2(S); lane reg q4*4+i -> k_local = i + 8*q4 + 4h, q = c
            float tv[16];
#pragma unroll
            for (int i = 0; i < 16; i++) { tv[i] = EXP2(S[i]); rsum += tv[i]; }

            unsigned v0[4], v1[4];
#pragma unroll
            for (int q4 = 0; q4 < 4; q4++) {
                v0[q4] = cvtpk(tv[4 * q4], tv[4 * q4 + 1]);
                v1[q4] = cvtpk(tv[4 * q4 + 2], tv[4 * q4 + 3]);
            }

            // ---- PV: two K=16 steps; P rearranged so slot (h,j) <-> k = 8h+j
#pragma unroll
            for (int ks = 0; ks < 2; ks++) {
                unsigned a0 = v0[2 * ks], b0 = v0[2 * ks + 1];
                unsigned a1 = v1[2 * ks], b1 = v1[2 * ks + 1];
                plswap(a0, b0);
                plswap(a1, b1);
                u32x4 paw; paw[0] = a0; paw[1] = a1; paw[2] = b0; paw[3] = b1;
                bf16x8 pa = __builtin_bit_cast(bf16x8, paw);
#pragma unroll
                for (int dt = 0; dt < 2; dt++) {
                    bf16x8 vb = *(const bf16x8*)(Vv + ((dt * 32 + c) << 7) +
                                                 ((ktile * 64 + ks * 32 + h16) ^ sx));
                    acc[dt] = __builtin_amdgcn_mfma_f32_32x32x16_bf16(pa, vb, acc[dt], 0, 0, 0);
                }
            }
        }
        __syncthreads();
        bufi ^= 1;
    }

    // ---- merge the two key halves; normalize; write
    rsum += __shfl_xor(rsum, 32);       // full per-q denominator of this key half

    float* rsbuf = (float*)&smem[0][0][0];        // [8][32]
    float* sumbuf = (float*)&smem[0][0][0] + 256; // [4][32][64]
    if (h == 0) rsbuf[w * 32 + c] = rsum;
    if (w >= 4) {
#pragma unroll
        for (int q4 = 0; q4 < 4; q4++)
#pragma unroll
            for (int i = 0; i < 4; i++) {
                const int qrow = i + 8 * q4 + 4 * h;
#pragma unroll
                for (int dt = 0; dt < 2; dt++)
                    sumbuf[(((w - 4) * 32 + qrow) << 6) + dt * 32 + c] = acc[dt][q4 * 4 + i];
            }
    }
    __syncthreads();
    if (w < 4) {
        const int b = bh >> 4, hh = bh & 15;
#pragma unroll
        for (int q4 = 0; q4 < 4; q4++)
#pragma unroll
            for (int i = 0; i < 4; i++) {
                const int qrow = i + 8 * q4 + 4 * h;
                const float inv = 1.0f / (rsbuf[w * 32 + qrow] + rsbuf[(w + 4) * 32 + qrow]);
                short* op = Ctx + ((size_t)b * NS + qb + qrow) * ND + hh * HD;
#pragma unroll
                for (int dt = 0; dt < 2; dt++) {
                    const float vsum = acc[dt][q4 * 4 + i] +
                                       sumbuf[((w * 32 + qrow) << 6) + dt * 32 + c];
                    op[dt * 32 + c] = f2bf(vsum * inv);
                }
            }
    }
}

// ---------------------------------------------------------------------------
extern "C" void kernel_launch(void* const* d_in, const int* in_sizes, int n_in,
                              void* d_out, int out_size, void* d_ws, size_t ws_size,
                              hipStream_t stream) {
    (void)in_sizes; (void)n_in; (void)out_size; (void)ws_size;
    const float* query = (const float*)d_in[0];
    const float* key_  = (const float*)d_in[1];
    const float* value = (const float*)d_in[2];
    const float* Wq = (const float*)d_in[3];
    const float* bq = (const float*)d_in[4];
    const float* Wk = (const float*)d_in[5];
    const float* bk = (const float*)d_in[6];
    const float* Wv = (const float*)d_in[7];
    const float* bv = (const float*)d_in[8];
    const float* Wo = (const float*)d_in[9];
    const float* bo = (const float*)d_in[10];

    char* ws = (char*)d_ws;
    const size_t MB = 1024 * 1024;
    short* WtAll = (short*)ws;
    short* Qin = (short*)(ws + 8 * MB);
    short* Kin = (short*)(ws + 16 * MB);
    short* Vin = (short*)(ws + 24 * MB);
    short* Qb  = (short*)(ws + 32 * MB);
    short* Kb  = (short*)(ws + 40 * MB);
    short* Vtb = (short*)(ws + 48 * MB);
    short* Ctx = (short*)(ws + 8 * MB);   // reuse Qin

    prep_cast<<<dim3(2048, 1, 3), 256, 0, stream>>>(query, key_, value, Qin, Kin, Vin);
    prep_wt<<<dim3(32, 32, 4), 256, 0, stream>>>(Wq, Wk, Wv, Wo, WtAll);
    gemm_qkv<<<dim3(32, 8, 3), 256, 0, stream>>>(Qin, Kin, Vin, WtAll, bq, bk, bv,
                                                 Qb, Kb, Vtb);
    attn_kern<<<dim3(512), 512, 0, stream>>>(Qb, Kb, Vtb, Ctx);
    gemm_fin<<<dim3(32, 8), 256, 0, stream>>>(Ctx, WtAll + 3 * ND * ND, bo, (float*)d_out);
}